// Round 1
// baseline (34.090 us; speedup 1.0000x reference)
//
#include <hip/hip_runtime.h>

#define D_ROWS 136
#define B_COLS 131072            // 2^17 — power of two, enables & masking
#define NBLOCKS_MAIN 2048
#define NTHREADS 256

// ---------------------------------------------------------------------------
// Kernel 1: per-column weight  w[b] = (sum_j [attr==1]*total/num_j) * (sum_j 1-cos(ea_j))
// ---------------------------------------------------------------------------
__global__ __launch_bounds__(NTHREADS) void weight_kernel(
    const float* __restrict__ ea,        // [3][B]
    const int*   __restrict__ attr,      // [6][B]
    const float* __restrict__ attr_num,  // [6]
    float*       __restrict__ weight)    // [B]
{
    int b = blockIdx.x * blockDim.x + threadIdx.x;
    if (b >= B_COLS) return;

    float total = attr_num[0] + attr_num[1] + attr_num[2] +
                  attr_num[3] + attr_num[4] + attr_num[5];

    float aw = 0.f;
#pragma unroll
    for (int j = 0; j < 6; ++j) {
        int a = attr[j * B_COLS + b];
        aw += (a == 1) ? (total / attr_num[j]) : 0.f;
    }

    float angw = 0.f;
#pragma unroll
    for (int j = 0; j < 3; ++j) {
        angw += 1.f - cosf(ea[j * B_COLS + b]);
    }

    weight[b] = aw * angw;
}

// ---------------------------------------------------------------------------
// Kernel 2: grid-stride float4 weighted-SSE, per-block double partial
// ---------------------------------------------------------------------------
__global__ __launch_bounds__(NTHREADS) void mse_kernel(
    const float4* __restrict__ inp,
    const float4* __restrict__ label,
    const float*  __restrict__ weight,
    double*       __restrict__ partials)
{
    const long long n4 = (long long)D_ROWS * B_COLS / 4;
    const long long stride = (long long)gridDim.x * blockDim.x;

    float acc = 0.f;
    for (long long i = (long long)blockIdx.x * blockDim.x + threadIdx.x;
         i < n4; i += stride) {
        float4 a = inp[i];
        float4 l = label[i];
        long long base = (i * 4) & (long long)(B_COLS - 1);  // column index
        float4 w = *reinterpret_cast<const float4*>(weight + base);
        float dx = a.x - l.x;
        float dy = a.y - l.y;
        float dz = a.z - l.z;
        float dw = a.w - l.w;
        acc += w.x * dx * dx + w.y * dy * dy + w.z * dz * dz + w.w * dw * dw;
    }

    // wave (64-lane) shuffle reduce in float
    for (int off = 32; off > 0; off >>= 1)
        acc += __shfl_down(acc, off, 64);

    __shared__ double sw[NTHREADS / 64];
    int lane = threadIdx.x & 63;
    int wid  = threadIdx.x >> 6;
    if (lane == 0) sw[wid] = (double)acc;
    __syncthreads();
    if (threadIdx.x == 0) {
        double s = 0.0;
#pragma unroll
        for (int w = 0; w < NTHREADS / 64; ++w) s += sw[w];
        partials[blockIdx.x] = s;
    }
}

// ---------------------------------------------------------------------------
// Kernel 3: final reduce of block partials -> mean
// ---------------------------------------------------------------------------
__global__ __launch_bounds__(NTHREADS) void final_kernel(
    const double* __restrict__ partials,
    int n,
    float* __restrict__ out)
{
    double acc = 0.0;
    for (int i = threadIdx.x; i < n; i += blockDim.x) acc += partials[i];

    for (int off = 32; off > 0; off >>= 1)
        acc += __shfl_down(acc, off, 64);

    __shared__ double sw[NTHREADS / 64];
    int lane = threadIdx.x & 63;
    int wid  = threadIdx.x >> 6;
    if (lane == 0) sw[wid] = acc;
    __syncthreads();
    if (threadIdx.x == 0) {
        double s = 0.0;
#pragma unroll
        for (int w = 0; w < NTHREADS / 64; ++w) s += sw[w];
        out[0] = (float)(s / ((double)D_ROWS * (double)B_COLS));
    }
}

// ---------------------------------------------------------------------------
extern "C" void kernel_launch(void* const* d_in, const int* in_sizes, int n_in,
                              void* d_out, int out_size, void* d_ws, size_t ws_size,
                              hipStream_t stream) {
    const float* inp      = (const float*)d_in[0];   // [D][B]
    const float* label    = (const float*)d_in[1];   // [D][B]
    const float* ea       = (const float*)d_in[2];   // [3][B]
    const int*   attr     = (const int*)d_in[3];     // [6][B]
    const float* attr_num = (const float*)d_in[4];   // [6]
    float* out = (float*)d_out;

    // workspace layout: weight [B] floats, then partials [NBLOCKS_MAIN] doubles
    float*  weight   = (float*)d_ws;
    double* partials = (double*)((char*)d_ws + (size_t)B_COLS * sizeof(float));

    weight_kernel<<<B_COLS / NTHREADS, NTHREADS, 0, stream>>>(
        ea, attr, attr_num, weight);

    mse_kernel<<<NBLOCKS_MAIN, NTHREADS, 0, stream>>>(
        (const float4*)inp, (const float4*)label, weight, partials);

    final_kernel<<<1, NTHREADS, 0, stream>>>(partials, NBLOCKS_MAIN, out);
}

// Round 2
// 33.973 us; speedup vs baseline: 1.0034x; 1.0034x over previous
//
#include <hip/hip_runtime.h>

#define D_ROWS 136
#define B_COLS 131072            // 2^17
#define NTHREADS 256
#define ROW_CHUNKS 8             // 136 / 8 = 17 rows per chunk
#define ROWS_PER_CHUNK (D_ROWS / ROW_CHUNKS)
#define CQ_TOTAL (B_COLS / 4)    // 32768 column-quads
#define CQ_BLOCKS (CQ_TOTAL / NTHREADS)   // 128
#define NPARTIALS (CQ_BLOCKS * ROW_CHUNKS) // 1024

// ---------------------------------------------------------------------------
// Kernel 1: per-column weight  w[b] = (sum_j [attr==1]*total/num_j) * (sum_j 1-cos(ea_j))
// Vectorized: each thread computes 4 columns.
// ---------------------------------------------------------------------------
__global__ __launch_bounds__(NTHREADS) void weight_kernel(
    const float4* __restrict__ ea,        // [3][B/4]
    const int4*   __restrict__ attr,      // [6][B/4]
    const float*  __restrict__ attr_num,  // [6]
    float4*       __restrict__ weight)    // [B/4]
{
    int cq = blockIdx.x * blockDim.x + threadIdx.x;
    if (cq >= CQ_TOTAL) return;

    float total = attr_num[0] + attr_num[1] + attr_num[2] +
                  attr_num[3] + attr_num[4] + attr_num[5];

    float aw[4] = {0.f, 0.f, 0.f, 0.f};
#pragma unroll
    for (int j = 0; j < 6; ++j) {
        int4 a = attr[j * CQ_TOTAL + cq];
        float f = total / attr_num[j];
        aw[0] += (a.x == 1) ? f : 0.f;
        aw[1] += (a.y == 1) ? f : 0.f;
        aw[2] += (a.z == 1) ? f : 0.f;
        aw[3] += (a.w == 1) ? f : 0.f;
    }

    float angw[4] = {0.f, 0.f, 0.f, 0.f};
#pragma unroll
    for (int j = 0; j < 3; ++j) {
        float4 e = ea[j * CQ_TOTAL + cq];
        angw[0] += 1.f - cosf(e.x);
        angw[1] += 1.f - cosf(e.y);
        angw[2] += 1.f - cosf(e.z);
        angw[3] += 1.f - cosf(e.w);
    }

    float4 w;
    w.x = aw[0] * angw[0];
    w.y = aw[1] * angw[1];
    w.z = aw[2] * angw[2];
    w.w = aw[3] * angw[3];
    weight[cq] = w;
}

// ---------------------------------------------------------------------------
// Kernel 2: each thread owns one column-quad for a 17-row chunk.
// Weight loaded ONCE per thread; rows walked with unrolled loop for ILP.
// ---------------------------------------------------------------------------
__global__ __launch_bounds__(NTHREADS) void mse_kernel(
    const float4* __restrict__ inp,
    const float4* __restrict__ label,
    const float4* __restrict__ weight4,
    double*       __restrict__ partials)
{
    const int cq = blockIdx.x * blockDim.x + threadIdx.x;   // 0..32767
    const int r0 = blockIdx.y * ROWS_PER_CHUNK;
    const int stride4 = CQ_TOTAL;                           // float4 row stride

    float4 w = weight4[cq];
    float acc = 0.f;

    int idx = r0 * stride4 + cq;
#pragma unroll 4
    for (int r = 0; r < ROWS_PER_CHUNK; ++r) {
        float4 a = inp[idx];
        float4 l = label[idx];
        float dx = a.x - l.x;
        float dy = a.y - l.y;
        float dz = a.z - l.z;
        float dw = a.w - l.w;
        acc += w.x * dx * dx + w.y * dy * dy + w.z * dz * dz + w.w * dw * dw;
        idx += stride4;
    }

    // 64-lane wave shuffle reduce
    for (int off = 32; off > 0; off >>= 1)
        acc += __shfl_down(acc, off, 64);

    __shared__ double sw[NTHREADS / 64];
    int lane = threadIdx.x & 63;
    int wid  = threadIdx.x >> 6;
    if (lane == 0) sw[wid] = (double)acc;
    __syncthreads();
    if (threadIdx.x == 0) {
        double s = 0.0;
#pragma unroll
        for (int v = 0; v < NTHREADS / 64; ++v) s += sw[v];
        partials[blockIdx.y * gridDim.x + blockIdx.x] = s;
    }
}

// ---------------------------------------------------------------------------
// Kernel 3: final reduce of block partials -> mean
// ---------------------------------------------------------------------------
__global__ __launch_bounds__(NTHREADS) void final_kernel(
    const double* __restrict__ partials,
    int n,
    float* __restrict__ out)
{
    double acc = 0.0;
    for (int i = threadIdx.x; i < n; i += blockDim.x) acc += partials[i];

    for (int off = 32; off > 0; off >>= 1)
        acc += __shfl_down(acc, off, 64);

    __shared__ double sw[NTHREADS / 64];
    int lane = threadIdx.x & 63;
    int wid  = threadIdx.x >> 6;
    if (lane == 0) sw[wid] = acc;
    __syncthreads();
    if (threadIdx.x == 0) {
        double s = 0.0;
#pragma unroll
        for (int v = 0; v < NTHREADS / 64; ++v) s += sw[v];
        out[0] = (float)(s / ((double)D_ROWS * (double)B_COLS));
    }
}

// ---------------------------------------------------------------------------
extern "C" void kernel_launch(void* const* d_in, const int* in_sizes, int n_in,
                              void* d_out, int out_size, void* d_ws, size_t ws_size,
                              hipStream_t stream) {
    const float* inp      = (const float*)d_in[0];   // [D][B]
    const float* label    = (const float*)d_in[1];   // [D][B]
    const float* ea       = (const float*)d_in[2];   // [3][B]
    const int*   attr     = (const int*)d_in[3];     // [6][B]
    const float* attr_num = (const float*)d_in[4];   // [6]
    float* out = (float*)d_out;

    // workspace layout: weight [B] floats, then partials [NPARTIALS] doubles
    float*  weight   = (float*)d_ws;
    double* partials = (double*)((char*)d_ws + (size_t)B_COLS * sizeof(float));

    weight_kernel<<<CQ_TOTAL / NTHREADS, NTHREADS, 0, stream>>>(
        (const float4*)ea, (const int4*)attr, attr_num, (float4*)weight);

    mse_kernel<<<dim3(CQ_BLOCKS, ROW_CHUNKS), NTHREADS, 0, stream>>>(
        (const float4*)inp, (const float4*)label, (const float4*)weight, partials);

    final_kernel<<<1, NTHREADS, 0, stream>>>(partials, NPARTIALS, out);
}